// Round 1
// baseline (539.325 us; speedup 1.0000x reference)
//
#include <hip/hip_runtime.h>
#include <hip/hip_fp8.h>

#define N_NODES 100000
#define N_EDGES 1600000
#define BN_EPS 1e-5f
#define NB_SCAN 98       // ceil(100000/1024)
#define PART_SZ 12500    // N_NODES / 8 XCD partitions
#define FILL_CHUNKS 1000
#define CHUNK_I4 400     // int4s per chunk: 1000 * 400 * 4 = 1.6M edges exact

typedef float v2f __attribute__((ext_vector_type(2)));

// broadcast lane k's value (readlane). Wave-uniform control flow ONLY.
__device__ __forceinline__ float bcast(float v, int k) {
    return __uint_as_float(__builtin_amdgcn_readlane(__float_as_uint(v), k));
}
__device__ __forceinline__ unsigned short f2bf(float x) {   // round-nearest-even
    unsigned int u = __float_as_uint(x);
    return (unsigned short)((u + 0x7FFF + ((u >> 16) & 1)) >> 16);
}
// fp8 e4m3 encode (cold path: once per element in the dense kernels)
__device__ __forceinline__ unsigned char f2fp8(float x) {
    return (unsigned char)__hip_cvt_float_to_fp8(x, __HIP_SATFINITE, __HIP_E4M3);
}
// HW packed decode: 2 x fp8(e4m3) -> 2 x f32 in ONE VALU instruction.
// HI must be a compile-time constant: the builtin's byte-select operand is
// an immediate (R15 failed passing a runtime bool) -> template parameter.
template <bool HI>
__device__ __forceinline__ v2f fp8x2(unsigned int w) {
#if __has_builtin(__builtin_amdgcn_cvt_pk_f32_fp8)
    return __builtin_amdgcn_cvt_pk_f32_fp8((int)w, HI);
#else
    unsigned int b = HI ? (w >> 16) : w;
    __half_raw h0 = __hip_cvt_fp8_to_halfraw((__hip_fp8_storage_t)(b & 0xFF), __HIP_E4M3);
    __half_raw h1 = __hip_cvt_fp8_to_halfraw((__hip_fp8_storage_t)((b >> 8) & 0xFF), __HIP_E4M3);
    v2f r; r.x = __half2float(__half(h0)); r.y = __half2float(__half(h1));
    return r;
#endif
}

// ===========================================================================
// CSR build, XCD-partitioned (R10) + int4-vectorized edge reads:
// 4 edges per load instruction; grid = FILL_CHUNKS x 8.
// ===========================================================================
__global__ __launch_bounds__(256) void histogram_xcd_kernel(
    const int4* __restrict__ dst4, int* __restrict__ deg)
{
    int part = blockIdx.x & 7;
    int lo = part * PART_SZ, hi = lo + PART_SZ;
    int base = (blockIdx.x >> 3) * CHUNK_I4;
    for (int i = threadIdx.x; i < CHUNK_I4; i += 256) {
        int4 d = dst4[base + i];
        if (d.x >= lo && d.x < hi) atomicAdd(&deg[d.x], 1);
        if (d.y >= lo && d.y < hi) atomicAdd(&deg[d.y], 1);
        if (d.z >= lo && d.z < hi) atomicAdd(&deg[d.z], 1);
        if (d.w >= lo && d.w < hi) atomicAdd(&deg[d.w], 1);
    }
}

__global__ __launch_bounds__(256) void fill_xcd_kernel(
    const int4* __restrict__ src4, const int4* __restrict__ dst4,
    int* __restrict__ cursor, int* __restrict__ nbr)
{
    int part = blockIdx.x & 7;
    int lo = part * PART_SZ, hi = lo + PART_SZ;
    int base = (blockIdx.x >> 3) * CHUNK_I4;
    for (int i = threadIdx.x; i < CHUNK_I4; i += 256) {
        int4 d = dst4[base + i];
        int4 s = src4[base + i];
        if (d.x >= lo && d.x < hi) { int p = atomicAdd(&cursor[d.x], 1); nbr[p] = s.x; }
        if (d.y >= lo && d.y < hi) { int p = atomicAdd(&cursor[d.y], 1); nbr[p] = s.y; }
        if (d.z >= lo && d.z < hi) { int p = atomicAdd(&cursor[d.z], 1); nbr[p] = s.z; }
        if (d.w >= lo && d.w < hi) { int p = atomicAdd(&cursor[d.w], 1); nbr[p] = s.w; }
    }
}

__global__ __launch_bounds__(1024) void scan1_kernel(
    const int* __restrict__ deg, int* __restrict__ offs, int* __restrict__ bsum)
{
    __shared__ int tmp[1024];
    int gid = blockIdx.x * 1024 + threadIdx.x;
    int v = (gid < N_NODES) ? deg[gid] : 0;
    tmp[threadIdx.x] = v;
    __syncthreads();
    for (int off = 1; off < 1024; off <<= 1) {
        int t = (threadIdx.x >= off) ? tmp[threadIdx.x - off] : 0;
        __syncthreads();
        tmp[threadIdx.x] += t;
        __syncthreads();
    }
    if (gid < N_NODES) offs[gid] = tmp[threadIdx.x] - v;
    if (threadIdx.x == 1023) bsum[blockIdx.x] = tmp[1023];
}

// scan3b: each block redundantly reduces bsum for its base offset.
__global__ __launch_bounds__(1024) void scan3b_kernel(
    int* __restrict__ offs, const int* __restrict__ bsum, int* __restrict__ cursor)
{
    __shared__ int red[128];
    int tid = threadIdx.x;
    if (tid < 128) red[tid] = (tid < (int)blockIdx.x && tid < NB_SCAN) ? bsum[tid] : 0;
    __syncthreads();
    if (tid < 64) red[tid] += red[tid + 64];
    __syncthreads();
    if (tid < 32) red[tid] += red[tid + 32];
    __syncthreads();
    if (tid < 16) red[tid] += red[tid + 16];
    __syncthreads();
    if (tid < 8)  red[tid] += red[tid + 8];
    __syncthreads();
    if (tid < 4)  red[tid] += red[tid + 4];
    __syncthreads();
    if (tid < 2)  red[tid] += red[tid + 2];
    __syncthreads();
    if (tid == 0) red[0] += red[1];
    __syncthreads();
    int base = red[0];
    int gid = blockIdx.x * 1024 + tid;
    if (gid < N_NODES) {
        int v = offs[gid] + base;
        offs[gid] = v;
        cursor[gid] = v;
    }
    if (gid == N_NODES) offs[N_NODES] = N_EDGES;
}

// ===========================================================================
// dense1_lin: u(fp8 e4m3, 64B rows = 1 line) = x @ W1l^T ;
// hv(f32) = x @ W1r^T + b1.
// ===========================================================================
__global__ __launch_bounds__(256) void dense1_lin_kernel(
    const float* __restrict__ x, const float* __restrict__ W1l,
    const float* __restrict__ W1r, const float* __restrict__ b1,
    unsigned char* __restrict__ u8, float* __restrict__ hv)
{
    __shared__ float wlT[64 * 65];
    __shared__ float wrT[64 * 65];
    for (int idx = threadIdx.x; idx < 4096; idx += 256) {
        int f = idx >> 6, k = idx & 63;
        wlT[k * 65 + f] = W1l[idx];
        wrT[k * 65 + f] = W1r[idx];
    }
    __syncthreads();

    int f  = threadIdx.x & 63;
    int wv = threadIdx.x >> 6;
    float wl[64], wr[64];
#pragma unroll
    for (int k = 0; k < 64; ++k) {
        wl[k] = wlT[k * 65 + f];
        wr[k] = wrT[k * 65 + f];
    }
    float bias = b1[f];
    int node0 = blockIdx.x * 64;

    for (int nn = 0; nn < 16; ++nn) {
        int node = node0 + nn * 4 + wv;          // wave-uniform
        if (node < N_NODES) {
            float xv = x[(size_t)node * 64 + f];
            float ua = 0.f, va = bias;
#pragma unroll
            for (int k = 0; k < 64; ++k) {
                float xb = bcast(xv, k);
                ua += xb * wl[k];
                va += xb * wr[k];
            }
            u8[(size_t)node * 64 + f] = f2fp8(ua);   // coalesced 64B/node
            hv[(size_t)node * 64 + f] = va;
        }
    }
}

// ===========================================================================
// gather1_bn v9 (R16): quarter-wave node parallelism for 4x MLP.
// One node per 16 lanes (4 nodes/wave concurrently); lane m owns the 4
// features in dword m of the fp8 row. Fully-unrolled 16-edge inner loop
// issues 16 loads x 4 lines = 64 cache lines in flight per wave (was 16).
// offs staged in LDS (removes one serial global hop). No cross-lane
// feature reduction needed; hv RMW is all-lane coalesced float4.
// ===========================================================================
__global__ __launch_bounds__(256) void gather1_bn_kernel(
    const unsigned int* __restrict__ u32, const int* __restrict__ offs,
    const int* __restrict__ nbr, float* __restrict__ hv,
    float* __restrict__ sums, float* __restrict__ sumsq)
{
    __shared__ int soffs[65];
    __shared__ float4 redA[256];
    __shared__ float4 redB[256];

    int node0 = blockIdx.x * 64;
    if (threadIdx.x < 65) {
        int n = node0 + threadIdx.x;
        soffs[threadIdx.x] = offs[(n < N_NODES) ? n : N_NODES];
    }
    __syncthreads();

    int lane = threadIdx.x & 63;
    int wv   = threadIdx.x >> 6;
    int q    = lane >> 4;          // quarter 0..3 = node within group of 4
    int m    = lane & 15;          // dword within 64B fp8 row = feats 4m..4m+3

    float4 s1 = make_float4(0.f, 0.f, 0.f, 0.f);
    float4 s2 = make_float4(0.f, 0.f, 0.f, 0.f);

    for (int nn = 0; nn < 4; ++nn) {
        int li   = wv * 16 + nn * 4 + q;   // local node 0..63
        int node = node0 + li;
        int beg = soffs[li], end = soffs[li + 1];
        int deg = end - beg;

        // prefetch hv row early: overlaps with gather latency
        float4 v = make_float4(0.f, 0.f, 0.f, 0.f);
        if (node < N_NODES)
            v = ((const float4*)hv)[(size_t)node * 16 + m];

        // wave-uniform trip count = max deg over the 4 quarters
        int degmax = deg;
        degmax = max(degmax, __shfl_xor(degmax, 16));
        degmax = max(degmax, __shfl_xor(degmax, 32));

        float a0 = 0.f, a1 = 0.f, a2 = 0.f, a3 = 0.f;
        for (int c = 0; c < degmax; c += 16) {
            int idx = beg + c + m;          // this quarter's next 16 edge slots
            int id  = nbr[max(min(idx, end - 1), 0)];   // coalesced, clamped
            int cnt = min(deg - c, 16);     // may be <= 0 for short quarters
            unsigned int wbuf[16];
#pragma unroll
            for (int e = 0; e < 16; ++e) {  // all 16 loads issued before use
                int ide = __shfl(id, (q << 4) | e);
                wbuf[e] = u32[(size_t)ide * 16 + m];
            }
#pragma unroll
            for (int e = 0; e < 16; ++e) {
                unsigned int w = (e < cnt) ? wbuf[e] : 0u;
                v2f dlo = fp8x2<false>(w);
                v2f dhi = fp8x2<true>(w);
                a0 += dlo.x; a1 += dlo.y; a2 += dhi.x; a3 += dhi.y;
            }
        }

        if (node < N_NODES) {
            float inv = 1.0f / (float)max(deg, 1);
            float h0 = a0 * inv + v.x;
            float h1 = a1 * inv + v.y;
            float h2 = a2 * inv + v.z;
            float h3 = a3 * inv + v.w;
            ((float4*)hv)[(size_t)node * 16 + m] = make_float4(h0, h1, h2, h3);
            s1.x += h0; s1.y += h1; s1.z += h2; s1.w += h3;
            s2.x += h0 * h0; s2.y += h1 * h1; s2.z += h2 * h2; s2.w += h3 * h3;
        }
    }

    redA[threadIdx.x] = s1;
    redB[threadIdx.x] = s2;
    __syncthreads();
    if (threadIdx.x < 16) {
        float4 A = make_float4(0.f, 0.f, 0.f, 0.f);
        float4 B = make_float4(0.f, 0.f, 0.f, 0.f);
        for (int j = 0; j < 16; ++j) {       // all threads with m == tid
            float4 a = redA[j * 16 + threadIdx.x];
            float4 b = redB[j * 16 + threadIdx.x];
            A.x += a.x; A.y += a.y; A.z += a.z; A.w += a.w;
            B.x += b.x; B.y += b.y; B.z += b.z; B.w += b.w;
        }
        int f = threadIdx.x * 4;
        atomicAdd(&sums[f + 0], A.x);  atomicAdd(&sums[f + 1], A.y);
        atomicAdd(&sums[f + 2], A.z);  atomicAdd(&sums[f + 3], A.w);
        atomicAdd(&sumsq[f + 0], B.x); atomicAdd(&sumsq[f + 1], B.y);
        atomicAdd(&sumsq[f + 2], B.z); atomicAdd(&sumsq[f + 3], B.w);
    }
}

// ===========================================================================
// dense2_bn: BN finalize folded in; BN+ReLU per lane; projection tmp is
// ONE fp8 row per node (40B used, 64B stride = 1 line); out direct.
// ===========================================================================
__global__ __launch_bounds__(256) void dense2_bn_kernel(
    const float* __restrict__ h, const float* __restrict__ sums,
    const float* __restrict__ sumsq, const float* __restrict__ gamma,
    const float* __restrict__ beta, const float* __restrict__ W2l,
    const float* __restrict__ W2r, const float* __restrict__ b2,
    unsigned char* __restrict__ t40, float* __restrict__ out)
{
    __shared__ float wlT[64 * 65];
    __shared__ float wrT[64 * 65];
    for (int idx = threadIdx.x; idx < 2560; idx += 256) {
        int f = idx >> 6, k = idx & 63;      // f < 40
        wlT[k * 65 + f] = W2l[idx];
        wrT[k * 65 + f] = W2r[idx];
    }
    __syncthreads();

    int f  = threadIdx.x & 63;
    int wv = threadIdx.x >> 6;
    int fc = (f < 40) ? f : 39;
    float wl[64], wr[64];
#pragma unroll
    for (int k = 0; k < 64; ++k) {
        wl[k] = wlT[k * 65 + fc];
        wr[k] = wrT[k * 65 + fc];
    }
    float bias = b2[fc];

    // BN finalize (redundant per block, ~10 insts)
    float inv_n = 1.0f / (float)N_NODES;
    float mu  = sums[f] * inv_n;
    float var = sumsq[f] * inv_n - mu * mu;
    float rs  = rsqrtf(var + BN_EPS);
    float sc  = gamma[f] * rs;
    float sh  = beta[f] - mu * sc;

    int node0 = blockIdx.x * 64;

    for (int nn = 0; nn < 16; ++nn) {
        int node = node0 + nn * 4 + wv;          // wave-uniform
        if (node < N_NODES) {
            float hvv = h[(size_t)node * 64 + f];
            float hn  = fmaxf(hvv * sc + sh, 0.f);   // BN + ReLU fused
            float ta = 0.f, ra = bias;
#pragma unroll
            for (int k = 0; k < 64; ++k) {
                float hb = bcast(hn, k);
                ta += hb * wl[k];
                ra += hb * wr[k];
            }
            if (f < 40) {
                t40[(size_t)node * 64 + f] = f2fp8(ta);
                out[(size_t)node * 40 + f] = ra;
            }
        }
    }
}

// ===========================================================================
// gather2 v8 (R16): same quarter-wave restructure as gather1. One node per
// 16 lanes; lane m (clamped to dword 9) owns feats 4m..4m+3 of the 40B fp8
// row. 16 loads x 4 lines = 64 lines in flight per wave (was 16). Lanes
// m>=10 load a duplicate dword of the same line (no extra traffic) and
// never store. out RMW is float4-coalesced for lanes m<10.
// ===========================================================================
__global__ __launch_bounds__(256) void gather2_kernel(
    const unsigned int* __restrict__ t40, const int* __restrict__ offs,
    const int* __restrict__ nbr, float* __restrict__ out)
{
    __shared__ int soffs[65];
    int node0 = blockIdx.x * 64;
    if (threadIdx.x < 65) {
        int n = node0 + threadIdx.x;
        soffs[threadIdx.x] = offs[(n < N_NODES) ? n : N_NODES];
    }
    __syncthreads();

    int lane = threadIdx.x & 63;
    int wv   = threadIdx.x >> 6;
    int q    = lane >> 4;          // quarter = node within group of 4
    int m    = lane & 15;
    int cl   = (m < 10) ? m : 9;   // dword in 40B row

    for (int nn = 0; nn < 4; ++nn) {
        int li   = wv * 16 + nn * 4 + q;
        int node = node0 + li;
        int beg = soffs[li], end = soffs[li + 1];
        int deg = end - beg;

        float4 o = make_float4(0.f, 0.f, 0.f, 0.f);
        if (node < N_NODES && m < 10)
            o = ((const float4*)out)[(size_t)node * 10 + m];

        int degmax = deg;
        degmax = max(degmax, __shfl_xor(degmax, 16));
        degmax = max(degmax, __shfl_xor(degmax, 32));

        float a0 = 0.f, a1 = 0.f, a2 = 0.f, a3 = 0.f;
        for (int c = 0; c < degmax; c += 16) {
            int idx = beg + c + m;
            int id  = nbr[max(min(idx, end - 1), 0)];
            int cnt = min(deg - c, 16);
            unsigned int wbuf[16];
#pragma unroll
            for (int e = 0; e < 16; ++e) {
                int ide = __shfl(id, (q << 4) | e);
                wbuf[e] = t40[(size_t)ide * 16 + cl];
            }
#pragma unroll
            for (int e = 0; e < 16; ++e) {
                unsigned int w = (e < cnt) ? wbuf[e] : 0u;
                v2f dlo = fp8x2<false>(w);
                v2f dhi = fp8x2<true>(w);
                a0 += dlo.x; a1 += dlo.y; a2 += dhi.x; a3 += dhi.y;
            }
        }

        if (node < N_NODES && m < 10) {
            float inv = 1.0f / (float)max(deg, 1);
            o.x += a0 * inv;
            o.y += a1 * inv;
            o.z += a2 * inv;
            o.w += a3 * inv;
            ((float4*)out)[(size_t)node * 10 + m] = o;
        }
    }
}

extern "C" void kernel_launch(void* const* d_in, const int* in_sizes, int n_in,
                              void* d_out, int out_size, void* d_ws, size_t ws_size,
                              hipStream_t stream)
{
    const float* x     = (const float*)d_in[0];
    const int*   ei    = (const int*)d_in[1];
    const float* W1l   = (const float*)d_in[2];
    const float* W1r   = (const float*)d_in[3];
    const float* b1    = (const float*)d_in[4];
    const float* gamma = (const float*)d_in[5];
    const float* beta  = (const float*)d_in[6];
    const float* W2l   = (const float*)d_in[7];
    const float* W2r   = (const float*)d_in[8];
    const float* b2    = (const float*)d_in[9];
    float* out = (float*)d_out;

    const int4* src4 = (const int4*)ei;              // edge_index[0], 16B-aligned
    const int4* dst4 = (const int4*)(ei + N_EDGES);  // edge_index[1]

    // workspace layout (~39 MB; 58.8 MB available). 64B-aligned arrays.
    float* ws    = (float*)d_ws;
    float* hv    = ws;                               // f32 [N*64]
    float* sums  = hv + (size_t)N_NODES * 64;        // 64
    float* sumsq = sums + 64;                        // 64
    float* padf  = sumsq + 64;                       // 128 pad
    int* deg    = (int*)(padf + 128);                // N
    int* offs   = deg + N_NODES;                     // N+16 (padded)
    int* cursor = offs + N_NODES + 16;               // N
    int* bsum   = cursor + N_NODES;                  // 128
    // scratch: u8 (fp8 N*64B) until gather1; t40 (fp8 N*64B) reuses it.
    unsigned char* u8 = (unsigned char*)(bsum + 128);
    unsigned char* t40 = u8;
    int* nbr    = (int*)(u8 + (size_t)N_NODES * 64); // E

    dim3 blk(256);

    // ---- CSR build (XCD-partitioned, int4 reads) + stat zeroing ----
    (void)hipMemsetAsync(sums, 0, (size_t)(256 + N_NODES) * sizeof(int), stream);
    histogram_xcd_kernel<<<FILL_CHUNKS * 8, blk, 0, stream>>>(dst4, deg);
    scan1_kernel<<<NB_SCAN, 1024, 0, stream>>>(deg, offs, bsum);
    scan3b_kernel<<<NB_SCAN, 1024, 0, stream>>>(offs, bsum, cursor);
    fill_xcd_kernel<<<FILL_CHUNKS * 8, blk, 0, stream>>>(src4, dst4, cursor, nbr);

    int dblocks = (N_NODES + 63) / 64;
    int gblocks = (N_NODES + 63) / 64;

    // ---- layer 1 ----
    dense1_lin_kernel<<<dblocks, blk, 0, stream>>>(x, W1l, W1r, b1, u8, hv);
    gather1_bn_kernel<<<gblocks, blk, 0, stream>>>(
        (const unsigned int*)u8, offs, nbr, hv, sums, sumsq);

    // ---- layer 2 (BN finalize + BN+ReLU fused into dense2) ----
    dense2_bn_kernel<<<dblocks, blk, 0, stream>>>(
        hv, sums, sumsq, gamma, beta, W2l, W2r, b2, t40, out);
    gather2_kernel<<<gblocks, blk, 0, stream>>>(
        (const unsigned int*)t40, offs, nbr, out);
}

// Round 2
// 486.724 us; speedup vs baseline: 1.1081x; 1.1081x over previous
//
#include <hip/hip_runtime.h>
#include <hip/hip_fp8.h>

#define N_NODES 100000
#define N_EDGES 1600000
#define BN_EPS 1e-5f
#define NB_SCAN 98       // ceil(100000/1024)
#define PART_SZ 12500    // N_NODES / 8 XCD partitions
#define FILL_CHUNKS 1000
#define CHUNK_I4 400     // int4s per chunk: 1000 * 400 * 4 = 1.6M edges exact

typedef float v2f __attribute__((ext_vector_type(2)));

// broadcast lane k's value (readlane). Wave-uniform control flow ONLY.
__device__ __forceinline__ float bcast(float v, int k) {
    return __uint_as_float(__builtin_amdgcn_readlane(__float_as_uint(v), k));
}
__device__ __forceinline__ unsigned short f2bf(float x) {   // round-nearest-even
    unsigned int u = __float_as_uint(x);
    return (unsigned short)((u + 0x7FFF + ((u >> 16) & 1)) >> 16);
}
// fp8 e4m3 encode (cold path: once per element in the dense kernels)
__device__ __forceinline__ unsigned char f2fp8(float x) {
    return (unsigned char)__hip_cvt_float_to_fp8(x, __HIP_SATFINITE, __HIP_E4M3);
}
// HW packed decode: 2 x fp8(e4m3) -> 2 x f32 in ONE VALU instruction.
// HI must be a compile-time constant: the builtin's byte-select operand is
// an immediate (R15 failed passing a runtime bool) -> template parameter.
template <bool HI>
__device__ __forceinline__ v2f fp8x2(unsigned int w) {
#if __has_builtin(__builtin_amdgcn_cvt_pk_f32_fp8)
    return __builtin_amdgcn_cvt_pk_f32_fp8((int)w, HI);
#else
    unsigned int b = HI ? (w >> 16) : w;
    __half_raw h0 = __hip_cvt_fp8_to_halfraw((__hip_fp8_storage_t)(b & 0xFF), __HIP_E4M3);
    __half_raw h1 = __hip_cvt_fp8_to_halfraw((__hip_fp8_storage_t)((b >> 8) & 0xFF), __HIP_E4M3);
    v2f r; r.x = __half2float(__half(h0)); r.y = __half2float(__half(h1));
    return r;
#endif
}

// ===========================================================================
// CSR build, XCD-partitioned (R10) + int4-vectorized edge reads:
// 4 edges per load instruction; grid = FILL_CHUNKS x 8.
// ===========================================================================
__global__ __launch_bounds__(256) void histogram_xcd_kernel(
    const int4* __restrict__ dst4, int* __restrict__ deg)
{
    int part = blockIdx.x & 7;
    int lo = part * PART_SZ, hi = lo + PART_SZ;
    int base = (blockIdx.x >> 3) * CHUNK_I4;
    for (int i = threadIdx.x; i < CHUNK_I4; i += 256) {
        int4 d = dst4[base + i];
        if (d.x >= lo && d.x < hi) atomicAdd(&deg[d.x], 1);
        if (d.y >= lo && d.y < hi) atomicAdd(&deg[d.y], 1);
        if (d.z >= lo && d.z < hi) atomicAdd(&deg[d.z], 1);
        if (d.w >= lo && d.w < hi) atomicAdd(&deg[d.w], 1);
    }
}

__global__ __launch_bounds__(256) void fill_xcd_kernel(
    const int4* __restrict__ src4, const int4* __restrict__ dst4,
    int* __restrict__ cursor, int* __restrict__ nbr)
{
    int part = blockIdx.x & 7;
    int lo = part * PART_SZ, hi = lo + PART_SZ;
    int base = (blockIdx.x >> 3) * CHUNK_I4;
    for (int i = threadIdx.x; i < CHUNK_I4; i += 256) {
        int4 d = dst4[base + i];
        int4 s = src4[base + i];
        if (d.x >= lo && d.x < hi) { int p = atomicAdd(&cursor[d.x], 1); nbr[p] = s.x; }
        if (d.y >= lo && d.y < hi) { int p = atomicAdd(&cursor[d.y], 1); nbr[p] = s.y; }
        if (d.z >= lo && d.z < hi) { int p = atomicAdd(&cursor[d.z], 1); nbr[p] = s.z; }
        if (d.w >= lo && d.w < hi) { int p = atomicAdd(&cursor[d.w], 1); nbr[p] = s.w; }
    }
}

__global__ __launch_bounds__(1024) void scan1_kernel(
    const int* __restrict__ deg, int* __restrict__ offs, int* __restrict__ bsum)
{
    __shared__ int tmp[1024];
    int gid = blockIdx.x * 1024 + threadIdx.x;
    int v = (gid < N_NODES) ? deg[gid] : 0;
    tmp[threadIdx.x] = v;
    __syncthreads();
    for (int off = 1; off < 1024; off <<= 1) {
        int t = (threadIdx.x >= off) ? tmp[threadIdx.x - off] : 0;
        __syncthreads();
        tmp[threadIdx.x] += t;
        __syncthreads();
    }
    if (gid < N_NODES) offs[gid] = tmp[threadIdx.x] - v;
    if (threadIdx.x == 1023) bsum[blockIdx.x] = tmp[1023];
}

// scan3b: each block redundantly reduces bsum for its base offset.
__global__ __launch_bounds__(1024) void scan3b_kernel(
    int* __restrict__ offs, const int* __restrict__ bsum, int* __restrict__ cursor)
{
    __shared__ int red[128];
    int tid = threadIdx.x;
    if (tid < 128) red[tid] = (tid < (int)blockIdx.x && tid < NB_SCAN) ? bsum[tid] : 0;
    __syncthreads();
    if (tid < 64) red[tid] += red[tid + 64];
    __syncthreads();
    if (tid < 32) red[tid] += red[tid + 32];
    __syncthreads();
    if (tid < 16) red[tid] += red[tid + 16];
    __syncthreads();
    if (tid < 8)  red[tid] += red[tid + 8];
    __syncthreads();
    if (tid < 4)  red[tid] += red[tid + 4];
    __syncthreads();
    if (tid < 2)  red[tid] += red[tid + 2];
    __syncthreads();
    if (tid == 0) red[0] += red[1];
    __syncthreads();
    int base = red[0];
    int gid = blockIdx.x * 1024 + tid;
    if (gid < N_NODES) {
        int v = offs[gid] + base;
        offs[gid] = v;
        cursor[gid] = v;
    }
    if (gid == N_NODES) offs[N_NODES] = N_EDGES;
}

// ===========================================================================
// dense1_lin: u(fp8 e4m3, 64B rows = 1 line) = x @ W1l^T ;
// hv(f32) = x @ W1r^T + b1.
// ===========================================================================
__global__ __launch_bounds__(256) void dense1_lin_kernel(
    const float* __restrict__ x, const float* __restrict__ W1l,
    const float* __restrict__ W1r, const float* __restrict__ b1,
    unsigned char* __restrict__ u8, float* __restrict__ hv)
{
    __shared__ float wlT[64 * 65];
    __shared__ float wrT[64 * 65];
    for (int idx = threadIdx.x; idx < 4096; idx += 256) {
        int f = idx >> 6, k = idx & 63;
        wlT[k * 65 + f] = W1l[idx];
        wrT[k * 65 + f] = W1r[idx];
    }
    __syncthreads();

    int f  = threadIdx.x & 63;
    int wv = threadIdx.x >> 6;
    float wl[64], wr[64];
#pragma unroll
    for (int k = 0; k < 64; ++k) {
        wl[k] = wlT[k * 65 + f];
        wr[k] = wrT[k * 65 + f];
    }
    float bias = b1[f];
    int node0 = blockIdx.x * 64;

    for (int nn = 0; nn < 16; ++nn) {
        int node = node0 + nn * 4 + wv;          // wave-uniform
        if (node < N_NODES) {
            float xv = x[(size_t)node * 64 + f];
            float ua = 0.f, va = bias;
#pragma unroll
            for (int k = 0; k < 64; ++k) {
                float xb = bcast(xv, k);
                ua += xb * wl[k];
                va += xb * wr[k];
            }
            u8[(size_t)node * 64 + f] = f2fp8(ua);   // coalesced 64B/node
            hv[(size_t)node * 64 + f] = va;
        }
    }
}

// ===========================================================================
// gather1_bn v10 (R17): v8's proven lane mapping + inner loop, byte-for-byte
// (109 us structure). Two chain-shortening additions ONLY:
//   (a) offs staged in LDS (removes ~200cy global hop per node),
//   (b) next node's nbr ids prefetched during current node's decode, and
//       hv float2 hoisted ahead of the gather (removes ~500cy nbr hop +
//       tail hv read from the per-node serial chain).
// ===========================================================================
__global__ __launch_bounds__(256) void gather1_bn_kernel(
    const unsigned short* __restrict__ u16, const int* __restrict__ offs,
    const int* __restrict__ nbr, float* __restrict__ hv,
    float* __restrict__ sums, float* __restrict__ sumsq)
{
    __shared__ int soffs[65];
    int node0 = blockIdx.x * 64;
    if (threadIdx.x < 65) {
        int n = node0 + threadIdx.x;
        soffs[threadIdx.x] = offs[(n < N_NODES) ? n : N_NODES];
    }
    __syncthreads();

    int lane = threadIdx.x & 63;
    int m    = lane & 31;
    int half = lane >> 5;
    int wv   = threadIdx.x >> 6;
    float s1_0 = 0.f, s1_1 = 0.f, s2_0 = 0.f, s2_1 = 0.f;

    // prefetch ids for the first node (clamped; safe for deg==0)
    int beg0 = soffs[wv], end0 = soffs[wv + 1];
    int idn = nbr[max(min(beg0 + lane, end0 - 1), 0)];

    for (int nn = 0; nn < 16; ++nn) {
        int li   = nn * 4 + wv;
        int node = node0 + li;
        int beg = soffs[li], end = soffs[li + 1];
        int deg = end - beg;
        int id  = idn;                        // ids for this node, chunk 0

        // prefetch next node's ids while this node's rows load/decode
        if (nn < 15) {
            int lin  = li + 4;
            int begn = soffs[lin], endn = soffs[lin + 1];
            idn = nbr[max(min(begn + lane, endn - 1), 0)];
        }

        if (node < N_NODES) {                    // wave-uniform
            // hoisted hv read: overlaps with the gather latency below
            float2 v = make_float2(0.f, 0.f);
            if (half == 0)
                v = ((const float2*)hv)[(size_t)node * 32 + m];

            float p0=0,p1=0,p2=0,p3=0,q0=0,q1=0,q2=0,q3=0;
            for (int c = 0; c < deg; c += 64) {  // ~always 1 iteration
                if (c > 0) {                     // rare: deg > 64
                    int idx = beg + c + lane;
                    id = nbr[(idx < end) ? idx : (end - 1)];
                }
                int cnt = min(deg - c, 64);
                for (int r = 0; r < cnt; r += 16) {   // wave-uniform trips
#pragma unroll
                    for (int i = 0; i < 8; ++i) {
                        int e   = r + 2 * i + half;   // < 64 always
                        int ide = __shfl(id, e);      // id from registers
                        unsigned int w = u16[(size_t)ide * 32 + m];
                        w = (e < cnt) ? w : 0u;       // mask packed word
                        v2f d = fp8x2<false>(w);      // 1 HW instruction
                        if ((i & 3) == 0)      { p0 += d.x; q0 += d.y; }
                        else if ((i & 3) == 1) { p1 += d.x; q1 += d.y; }
                        else if ((i & 3) == 2) { p2 += d.x; q2 += d.y; }
                        else                   { p3 += d.x; q3 += d.y; }
                    }
                }
            }
            float P = (p0 + p1) + (p2 + p3);
            float Q = (q0 + q1) + (q2 + q3);
            P += __shfl_xor(P, 32);    // combine the two half-waves
            Q += __shfl_xor(Q, 32);
            if (half == 0) {
                float inv = 1.0f / (float)max(deg, 1);
                float h0 = P * inv + v.x;
                float h1 = Q * inv + v.y;
                ((float2*)hv)[(size_t)node * 32 + m] = make_float2(h0, h1);
                s1_0 += h0; s1_1 += h1;
                s2_0 += h0 * h0; s2_1 += h1 * h1;
            }
        }
    }

    __shared__ float2 redA[256];
    __shared__ float2 redB[256];
    redA[threadIdx.x] = make_float2(s1_0, s1_1);
    redB[threadIdx.x] = make_float2(s2_0, s2_1);
    __syncthreads();
    if (threadIdx.x < 32) {
        int mm = threadIdx.x;
        float a0=0,a1=0,b0=0,b1=0;
        for (int w = 0; w < 4; ++w) {
            float2 A = redA[w * 64 + mm]; a0 += A.x; a1 += A.y;
            float2 B = redB[w * 64 + mm]; b0 += B.x; b1 += B.y;
        }
        atomicAdd(&sums[2 * mm], a0);  atomicAdd(&sums[2 * mm + 1], a1);
        atomicAdd(&sumsq[2 * mm], b0); atomicAdd(&sumsq[2 * mm + 1], b1);
    }
}

// ===========================================================================
// dense2_bn: BN finalize folded in; BN+ReLU per lane; projection tmp is
// ONE fp8 row per node (40B used, 64B stride = 1 line); out direct.
// ===========================================================================
__global__ __launch_bounds__(256) void dense2_bn_kernel(
    const float* __restrict__ h, const float* __restrict__ sums,
    const float* __restrict__ sumsq, const float* __restrict__ gamma,
    const float* __restrict__ beta, const float* __restrict__ W2l,
    const float* __restrict__ W2r, const float* __restrict__ b2,
    unsigned char* __restrict__ t40, float* __restrict__ out)
{
    __shared__ float wlT[64 * 65];
    __shared__ float wrT[64 * 65];
    for (int idx = threadIdx.x; idx < 2560; idx += 256) {
        int f = idx >> 6, k = idx & 63;      // f < 40
        wlT[k * 65 + f] = W2l[idx];
        wrT[k * 65 + f] = W2r[idx];
    }
    __syncthreads();

    int f  = threadIdx.x & 63;
    int wv = threadIdx.x >> 6;
    int fc = (f < 40) ? f : 39;
    float wl[64], wr[64];
#pragma unroll
    for (int k = 0; k < 64; ++k) {
        wl[k] = wlT[k * 65 + fc];
        wr[k] = wrT[k * 65 + fc];
    }
    float bias = b2[fc];

    // BN finalize (redundant per block, ~10 insts)
    float inv_n = 1.0f / (float)N_NODES;
    float mu  = sums[f] * inv_n;
    float var = sumsq[f] * inv_n - mu * mu;
    float rs  = rsqrtf(var + BN_EPS);
    float sc  = gamma[f] * rs;
    float sh  = beta[f] - mu * sc;

    int node0 = blockIdx.x * 64;

    for (int nn = 0; nn < 16; ++nn) {
        int node = node0 + nn * 4 + wv;          // wave-uniform
        if (node < N_NODES) {
            float hvv = h[(size_t)node * 64 + f];
            float hn  = fmaxf(hvv * sc + sh, 0.f);   // BN + ReLU fused
            float ta = 0.f, ra = bias;
#pragma unroll
            for (int k = 0; k < 64; ++k) {
                float hb = bcast(hn, k);
                ta += hb * wl[k];
                ra += hb * wr[k];
            }
            if (f < 40) {
                t40[(size_t)node * 64 + f] = f2fp8(ta);
                out[(size_t)node * 40 + f] = ra;
            }
        }
    }
}

// ===========================================================================
// gather2 v7 (round-0 proven): out += mean(t40[nbr]); t40 fp8, 40B used /
// 64B stride = ONE line per edge. Quarter-wave shape: 4 dword loads per
// 16-edge round (4 edges each; lane m<10 covers the row, m>=10 clamped to
// the same line). HW packed decode; invalid edges zero the word. Uniform
// flow; only the final store is predicated.
// ===========================================================================
__global__ __launch_bounds__(256) void gather2_kernel(
    const unsigned int* __restrict__ t40, const int* __restrict__ offs,
    const int* __restrict__ nbr, float* __restrict__ out)
{
    int lane = threadIdx.x & 63;
    int q    = lane >> 4;          // quarter 0..3
    int m    = lane & 15;          // dword in row; cl<10 used (feats 4cl..4cl+3)
    int cl   = (m < 10) ? m : 9;
    int wv   = threadIdx.x >> 6;
    int node0 = blockIdx.x * 64;

    for (int nn = 0; nn < 16; ++nn) {
        int node = node0 + nn * 4 + wv;
        if (node < N_NODES) {                    // wave-uniform
            int beg = offs[node], end = offs[node + 1];
            int deg = end - beg;
            float a0=0,a1=0,a2=0,a3=0, b0=0,b1=0,b2=0,b3=0;
            for (int c = 0; c < deg; c += 64) {
                int idx = beg + c + lane;
                int id  = nbr[(idx < end) ? idx : (end - 1)];  // coalesced
                int cnt = min(deg - c, 64);
                for (int r = 0; r < cnt; r += 16) {
#pragma unroll
                    for (int i = 0; i < 4; ++i) {   // 4 instrs x 4 edges
                        int e   = r + 4 * i + q;
                        int ide = __shfl(id, min(e, cnt - 1));
                        unsigned int w = t40[(size_t)ide * 16 + cl];
                        w = (e < cnt) ? w : 0u;     // mask packed word
                        v2f dlo = fp8x2<false>(w);
                        v2f dhi = fp8x2<true>(w);
                        if (i & 1) { b0 += dlo.x; b1 += dlo.y; b2 += dhi.x; b3 += dhi.y; }
                        else       { a0 += dlo.x; a1 += dlo.y; a2 += dhi.x; a3 += dhi.y; }
                    }
                }
            }
            a0 += b0; a1 += b1; a2 += b2; a3 += b3;
            // combine quarters (all lanes active)
            a0 += __shfl_xor(a0, 16); a0 += __shfl_xor(a0, 32);
            a1 += __shfl_xor(a1, 16); a1 += __shfl_xor(a1, 32);
            a2 += __shfl_xor(a2, 16); a2 += __shfl_xor(a2, 32);
            a3 += __shfl_xor(a3, 16); a3 += __shfl_xor(a3, 32);
            if (lane < 10) {          // quarter 0, dwords 0..9 = feats 4m..4m+3
                float inv = 1.0f / (float)max(deg, 1);
                float4 o = ((float4*)out)[(size_t)node * 10 + m];
                o.x += a0 * inv;
                o.y += a1 * inv;
                o.z += a2 * inv;
                o.w += a3 * inv;
                ((float4*)out)[(size_t)node * 10 + m] = o;
            }
        }
    }
}

extern "C" void kernel_launch(void* const* d_in, const int* in_sizes, int n_in,
                              void* d_out, int out_size, void* d_ws, size_t ws_size,
                              hipStream_t stream)
{
    const float* x     = (const float*)d_in[0];
    const int*   ei    = (const int*)d_in[1];
    const float* W1l   = (const float*)d_in[2];
    const float* W1r   = (const float*)d_in[3];
    const float* b1    = (const float*)d_in[4];
    const float* gamma = (const float*)d_in[5];
    const float* beta  = (const float*)d_in[6];
    const float* W2l   = (const float*)d_in[7];
    const float* W2r   = (const float*)d_in[8];
    const float* b2    = (const float*)d_in[9];
    float* out = (float*)d_out;

    const int4* src4 = (const int4*)ei;              // edge_index[0], 16B-aligned
    const int4* dst4 = (const int4*)(ei + N_EDGES);  // edge_index[1]

    // workspace layout (~39 MB; 58.8 MB available). 64B-aligned arrays.
    float* ws    = (float*)d_ws;
    float* hv    = ws;                               // f32 [N*64]
    float* sums  = hv + (size_t)N_NODES * 64;        // 64
    float* sumsq = sums + 64;                        // 64
    float* padf  = sumsq + 64;                       // 128 pad
    int* deg    = (int*)(padf + 128);                // N
    int* offs   = deg + N_NODES;                     // N+16 (padded)
    int* cursor = offs + N_NODES + 16;               // N
    int* bsum   = cursor + N_NODES;                  // 128
    // scratch: u8 (fp8 N*64B) until gather1; t40 (fp8 N*64B) reuses it.
    unsigned char* u8 = (unsigned char*)(bsum + 128);
    unsigned char* t40 = u8;
    int* nbr    = (int*)(u8 + (size_t)N_NODES * 64); // E

    dim3 blk(256);

    // ---- CSR build (XCD-partitioned, int4 reads) + stat zeroing ----
    (void)hipMemsetAsync(sums, 0, (size_t)(256 + N_NODES) * sizeof(int), stream);
    histogram_xcd_kernel<<<FILL_CHUNKS * 8, blk, 0, stream>>>(dst4, deg);
    scan1_kernel<<<NB_SCAN, 1024, 0, stream>>>(deg, offs, bsum);
    scan3b_kernel<<<NB_SCAN, 1024, 0, stream>>>(offs, bsum, cursor);
    fill_xcd_kernel<<<FILL_CHUNKS * 8, blk, 0, stream>>>(src4, dst4, cursor, nbr);

    int dblocks = (N_NODES + 63) / 64;
    int gblocks = (N_NODES + 63) / 64;

    // ---- layer 1 ----
    dense1_lin_kernel<<<dblocks, blk, 0, stream>>>(x, W1l, W1r, b1, u8, hv);
    gather1_bn_kernel<<<gblocks, blk, 0, stream>>>(
        (const unsigned short*)u8, offs, nbr, hv, sums, sumsq);

    // ---- layer 2 (BN finalize + BN+ReLU fused into dense2) ----
    dense2_bn_kernel<<<dblocks, blk, 0, stream>>>(
        hv, sums, sumsq, gamma, beta, W2l, W2r, b2, t40, out);
    gather2_kernel<<<gblocks, blk, 0, stream>>>(
        (const unsigned int*)t40, offs, nbr, out);
}

// Round 3
// 482.220 us; speedup vs baseline: 1.1184x; 1.0093x over previous
//
#include <hip/hip_runtime.h>
#include <hip/hip_fp8.h>

#define N_NODES 100000
#define N_EDGES 1600000
#define BN_EPS 1e-5f
#define NB_SCAN 98       // ceil(100000/1024)
#define PART_SZ 12500    // N_NODES / 8 XCD partitions
#define FILL_CHUNKS 1000
#define CHUNK_I4 400     // int4s per chunk: 1000 * 400 * 4 = 1.6M edges exact

typedef float v2f __attribute__((ext_vector_type(2)));

// broadcast lane k's value (readlane). Wave-uniform control flow ONLY.
__device__ __forceinline__ float bcast(float v, int k) {
    return __uint_as_float(__builtin_amdgcn_readlane(__float_as_uint(v), k));
}
__device__ __forceinline__ unsigned short f2bf(float x) {   // round-nearest-even
    unsigned int u = __float_as_uint(x);
    return (unsigned short)((u + 0x7FFF + ((u >> 16) & 1)) >> 16);
}
// fp8 e4m3 encode (cold path: once per element in the dense kernels)
__device__ __forceinline__ unsigned char f2fp8(float x) {
    return (unsigned char)__hip_cvt_float_to_fp8(x, __HIP_SATFINITE, __HIP_E4M3);
}
// HW packed decode: 2 x fp8(e4m3) -> 2 x f32 in ONE VALU instruction.
template <bool HI>
__device__ __forceinline__ v2f fp8x2(unsigned int w) {
#if __has_builtin(__builtin_amdgcn_cvt_pk_f32_fp8)
    return __builtin_amdgcn_cvt_pk_f32_fp8((int)w, HI);
#else
    unsigned int b = HI ? (w >> 16) : w;
    __half_raw h0 = __hip_cvt_fp8_to_halfraw((__hip_fp8_storage_t)(b & 0xFF), __HIP_E4M3);
    __half_raw h1 = __hip_cvt_fp8_to_halfraw((__hip_fp8_storage_t)((b >> 8) & 0xFF), __HIP_E4M3);
    v2f r; r.x = __half2float(__half(h0)); r.y = __half2float(__half(h1));
    return r;
#endif
}

// ===========================================================================
// CSR build, XCD-partitioned (R10) + int4-vectorized edge reads:
// 4 edges per load instruction; grid = FILL_CHUNKS x 8.
// ===========================================================================
__global__ __launch_bounds__(256) void histogram_xcd_kernel(
    const int4* __restrict__ dst4, int* __restrict__ deg)
{
    int part = blockIdx.x & 7;
    int lo = part * PART_SZ, hi = lo + PART_SZ;
    int base = (blockIdx.x >> 3) * CHUNK_I4;
    for (int i = threadIdx.x; i < CHUNK_I4; i += 256) {
        int4 d = dst4[base + i];
        if (d.x >= lo && d.x < hi) atomicAdd(&deg[d.x], 1);
        if (d.y >= lo && d.y < hi) atomicAdd(&deg[d.y], 1);
        if (d.z >= lo && d.z < hi) atomicAdd(&deg[d.z], 1);
        if (d.w >= lo && d.w < hi) atomicAdd(&deg[d.w], 1);
    }
}

__global__ __launch_bounds__(256) void fill_xcd_kernel(
    const int4* __restrict__ src4, const int4* __restrict__ dst4,
    int* __restrict__ cursor, int* __restrict__ nbr)
{
    int part = blockIdx.x & 7;
    int lo = part * PART_SZ, hi = lo + PART_SZ;
    int base = (blockIdx.x >> 3) * CHUNK_I4;
    for (int i = threadIdx.x; i < CHUNK_I4; i += 256) {
        int4 d = dst4[base + i];
        int4 s = src4[base + i];
        if (d.x >= lo && d.x < hi) { int p = atomicAdd(&cursor[d.x], 1); nbr[p] = s.x; }
        if (d.y >= lo && d.y < hi) { int p = atomicAdd(&cursor[d.y], 1); nbr[p] = s.y; }
        if (d.z >= lo && d.z < hi) { int p = atomicAdd(&cursor[d.z], 1); nbr[p] = s.z; }
        if (d.w >= lo && d.w < hi) { int p = atomicAdd(&cursor[d.w], 1); nbr[p] = s.w; }
    }
}

__global__ __launch_bounds__(1024) void scan1_kernel(
    const int* __restrict__ deg, int* __restrict__ offs, int* __restrict__ bsum)
{
    __shared__ int tmp[1024];
    int gid = blockIdx.x * 1024 + threadIdx.x;
    int v = (gid < N_NODES) ? deg[gid] : 0;
    tmp[threadIdx.x] = v;
    __syncthreads();
    for (int off = 1; off < 1024; off <<= 1) {
        int t = (threadIdx.x >= off) ? tmp[threadIdx.x - off] : 0;
        __syncthreads();
        tmp[threadIdx.x] += t;
        __syncthreads();
    }
    if (gid < N_NODES) offs[gid] = tmp[threadIdx.x] - v;
    if (threadIdx.x == 1023) bsum[blockIdx.x] = tmp[1023];
}

// scan3b: each block redundantly reduces bsum for its base offset.
__global__ __launch_bounds__(1024) void scan3b_kernel(
    int* __restrict__ offs, const int* __restrict__ bsum, int* __restrict__ cursor)
{
    __shared__ int red[128];
    int tid = threadIdx.x;
    if (tid < 128) red[tid] = (tid < (int)blockIdx.x && tid < NB_SCAN) ? bsum[tid] : 0;
    __syncthreads();
    if (tid < 64) red[tid] += red[tid + 64];
    __syncthreads();
    if (tid < 32) red[tid] += red[tid + 32];
    __syncthreads();
    if (tid < 16) red[tid] += red[tid + 16];
    __syncthreads();
    if (tid < 8)  red[tid] += red[tid + 8];
    __syncthreads();
    if (tid < 4)  red[tid] += red[tid + 4];
    __syncthreads();
    if (tid < 2)  red[tid] += red[tid + 2];
    __syncthreads();
    if (tid == 0) red[0] += red[1];
    __syncthreads();
    int base = red[0];
    int gid = blockIdx.x * 1024 + tid;
    if (gid < N_NODES) {
        int v = offs[gid] + base;
        offs[gid] = v;
        cursor[gid] = v;
    }
    if (gid == N_NODES) offs[N_NODES] = N_EDGES;
}

// ===========================================================================
// dense1_lin: u(fp8 e4m3, 64B rows = 1 line) = x @ W1l^T ;
// hv(f32) = x @ W1r^T + b1.
// ===========================================================================
__global__ __launch_bounds__(256) void dense1_lin_kernel(
    const float* __restrict__ x, const float* __restrict__ W1l,
    const float* __restrict__ W1r, const float* __restrict__ b1,
    unsigned char* __restrict__ u8, float* __restrict__ hv)
{
    __shared__ float wlT[64 * 65];
    __shared__ float wrT[64 * 65];
    for (int idx = threadIdx.x; idx < 4096; idx += 256) {
        int f = idx >> 6, k = idx & 63;
        wlT[k * 65 + f] = W1l[idx];
        wrT[k * 65 + f] = W1r[idx];
    }
    __syncthreads();

    int f  = threadIdx.x & 63;
    int wv = threadIdx.x >> 6;
    float wl[64], wr[64];
#pragma unroll
    for (int k = 0; k < 64; ++k) {
        wl[k] = wlT[k * 65 + f];
        wr[k] = wrT[k * 65 + f];
    }
    float bias = b1[f];
    int node0 = blockIdx.x * 64;

    for (int nn = 0; nn < 16; ++nn) {
        int node = node0 + nn * 4 + wv;          // wave-uniform
        if (node < N_NODES) {
            float xv = x[(size_t)node * 64 + f];
            float ua = 0.f, va = bias;
#pragma unroll
            for (int k = 0; k < 64; ++k) {
                float xb = bcast(xv, k);
                ua += xb * wl[k];
                va += xb * wr[k];
            }
            u8[(size_t)node * 64 + f] = f2fp8(ua);   // coalesced 64B/node
            hv[(size_t)node * 64 + f] = va;
        }
    }
}

// ===========================================================================
// gather1_bn v11 (R18): v8 lane mapping + decode byte-for-byte; NEW:
// cross-node software pipeline. At iter nn: issue node nn+2's ids and node
// nn+1's round-0 (+round-1 if its deg>16, wave-uniform) row loads into
// dedicated register buffers; decode node nn from already-arrived regs.
// Only memory wait per iteration is the rotation at iter end -> per-node
// cost max(L, body) instead of L + body. deg<=32 covers 99.98% of nodes;
// rounds >=2 and chunks >64 stay inline (rare).
// ===========================================================================
__global__ __launch_bounds__(256) void gather1_bn_kernel(
    const unsigned short* __restrict__ u16, const int* __restrict__ offs,
    const int* __restrict__ nbr, float* __restrict__ hv,
    float* __restrict__ sums, float* __restrict__ sumsq)
{
    __shared__ int soffs[65];
    int node0 = blockIdx.x * 64;
    if (threadIdx.x < 65) {
        int n = node0 + threadIdx.x;
        soffs[threadIdx.x] = offs[(n < N_NODES) ? n : N_NODES];
    }
    __syncthreads();

    int lane = threadIdx.x & 63;
    int m    = lane & 31;
    int half = lane >> 5;
    int wv   = threadIdx.x >> 6;
    float s1_0 = 0.f, s1_1 = 0.f, s2_0 = 0.f, s2_1 = 0.f;

    // ---- prologue: ids for nodes wv and wv+4 (issued back-to-back), then
    // rounds 0/1 rows of node wv.
    int idA, idB;
    {
        int bA = soffs[wv],     eA = soffs[wv + 1];
        int bB = soffs[wv + 4], eB = soffs[wv + 5];
        idA = nbr[max(min(bA + lane, eA - 1), 0)];
        idB = nbr[max(min(bB + lane, eB - 1), 0)];
    }
    unsigned int r0A[8], r1A[8], r0B[8], r1B[8];
    {
        int cnt0 = min(soffs[wv + 1] - soffs[wv], 64);
#pragma unroll
        for (int i = 0; i < 8; ++i) {
            int ide = __shfl(idA, 2 * i + half);
            r0A[i] = u16[(size_t)ide * 32 + m];
        }
        if (cnt0 > 16) {                     // wave-uniform
#pragma unroll
            for (int i = 0; i < 8; ++i) {
                int ide = __shfl(idA, 16 + 2 * i + half);
                r1A[i] = u16[(size_t)ide * 32 + m];
            }
        }
    }

    for (int nn = 0; nn < 16; ++nn) {
        int li   = nn * 4 + wv;
        int node = node0 + li;
        int beg = soffs[li], end = soffs[li + 1];
        int deg = end - beg;
        int cnt = min(deg, 64);

        // issue ids for node nn+2
        int idC = 0;
        if (nn < 14) {
            int b = soffs[li + 8], e = soffs[li + 9];
            idC = nbr[max(min(b + lane, e - 1), 0)];
        }
        // issue rounds 0/1 rows for node nn+1
        if (nn < 15) {
            int cntn = min(soffs[li + 5] - soffs[li + 4], 64);
#pragma unroll
            for (int i = 0; i < 8; ++i) {
                int ide = __shfl(idB, 2 * i + half);
                r0B[i] = u16[(size_t)ide * 32 + m];
            }
            if (cntn > 16) {                 // wave-uniform
#pragma unroll
                for (int i = 0; i < 8; ++i) {
                    int ide = __shfl(idB, 16 + 2 * i + half);
                    r1B[i] = u16[(size_t)ide * 32 + m];
                }
            }
        }

        if (node < N_NODES) {                    // wave-uniform
            float2 v = make_float2(0.f, 0.f);
            if (half == 0)
                v = ((const float2*)hv)[(size_t)node * 32 + m];

            float p0=0,p1=0,p2=0,p3=0,q0=0,q1=0,q2=0,q3=0;
            // round 0 from prefetched regs
#pragma unroll
            for (int i = 0; i < 8; ++i) {
                int e = 2 * i + half;
                unsigned int w = (e < cnt) ? r0A[i] : 0u;
                v2f d = fp8x2<false>(w);
                if ((i & 3) == 0)      { p0 += d.x; q0 += d.y; }
                else if ((i & 3) == 1) { p1 += d.x; q1 += d.y; }
                else if ((i & 3) == 2) { p2 += d.x; q2 += d.y; }
                else                   { p3 += d.x; q3 += d.y; }
            }
            if (cnt > 16) {                      // wave-uniform
                // round 1 from prefetched regs
#pragma unroll
                for (int i = 0; i < 8; ++i) {
                    int e = 16 + 2 * i + half;
                    unsigned int w = (e < cnt) ? r1A[i] : 0u;
                    v2f d = fp8x2<false>(w);
                    if ((i & 3) == 0)      { p0 += d.x; q0 += d.y; }
                    else if ((i & 3) == 1) { p1 += d.x; q1 += d.y; }
                    else if ((i & 3) == 2) { p2 += d.x; q2 += d.y; }
                    else                   { p3 += d.x; q3 += d.y; }
                }
                // rounds 2..3 inline (deg>32: ~0.02% of nodes)
                for (int r = 32; r < cnt; r += 16) {
#pragma unroll
                    for (int i = 0; i < 8; ++i) {
                        int e   = r + 2 * i + half;
                        int ide = __shfl(idA, e);
                        unsigned int w = u16[(size_t)ide * 32 + m];
                        w = (e < cnt) ? w : 0u;
                        v2f d = fp8x2<false>(w);
                        if ((i & 3) == 0)      { p0 += d.x; q0 += d.y; }
                        else if ((i & 3) == 1) { p1 += d.x; q1 += d.y; }
                        else if ((i & 3) == 2) { p2 += d.x; q2 += d.y; }
                        else                   { p3 += d.x; q3 += d.y; }
                    }
                }
            }
            // chunks beyond the first 64 edges (deg>64: negligible)
            for (int c = 64; c < deg; c += 64) {
                int idx = beg + c + lane;
                int idc = nbr[(idx < end) ? idx : (end - 1)];
                int cnt2 = min(deg - c, 64);
                for (int r = 0; r < cnt2; r += 16) {
#pragma unroll
                    for (int i = 0; i < 8; ++i) {
                        int e   = r + 2 * i + half;
                        int ide = __shfl(idc, e);
                        unsigned int w = u16[(size_t)ide * 32 + m];
                        w = (e < cnt2) ? w : 0u;
                        v2f d = fp8x2<false>(w);
                        if ((i & 3) == 0)      { p0 += d.x; q0 += d.y; }
                        else if ((i & 3) == 1) { p1 += d.x; q1 += d.y; }
                        else if ((i & 3) == 2) { p2 += d.x; q2 += d.y; }
                        else                   { p3 += d.x; q3 += d.y; }
                    }
                }
            }

            float P = (p0 + p1) + (p2 + p3);
            float Q = (q0 + q1) + (q2 + q3);
            P += __shfl_xor(P, 32);    // combine the two half-waves
            Q += __shfl_xor(Q, 32);
            if (half == 0) {
                float inv = 1.0f / (float)max(deg, 1);
                float h0 = P * inv + v.x;
                float h1 = Q * inv + v.y;
                ((float2*)hv)[(size_t)node * 32 + m] = make_float2(h0, h1);
                s1_0 += h0; s1_1 += h1;
                s2_0 += h0 * h0; s2_1 += h1 * h1;
            }
        }

        // rotate pipeline registers (waits for next node's rows here)
        idA = idB; idB = idC;
#pragma unroll
        for (int i = 0; i < 8; ++i) { r0A[i] = r0B[i]; r1A[i] = r1B[i]; }
    }

    __shared__ float2 redA[256];
    __shared__ float2 redB[256];
    redA[threadIdx.x] = make_float2(s1_0, s1_1);
    redB[threadIdx.x] = make_float2(s2_0, s2_1);
    __syncthreads();
    if (threadIdx.x < 32) {
        int mm = threadIdx.x;
        float a0=0,a1=0,b0=0,b1=0;
        for (int w = 0; w < 4; ++w) {
            float2 A = redA[w * 64 + mm]; a0 += A.x; a1 += A.y;
            float2 B = redB[w * 64 + mm]; b0 += B.x; b1 += B.y;
        }
        atomicAdd(&sums[2 * mm], a0);  atomicAdd(&sums[2 * mm + 1], a1);
        atomicAdd(&sumsq[2 * mm], b0); atomicAdd(&sumsq[2 * mm + 1], b1);
    }
}

// ===========================================================================
// dense2_bn: BN finalize folded in; BN+ReLU per lane; projection tmp is
// ONE fp8 row per node (40B used, 64B stride = 1 line); out direct.
// ===========================================================================
__global__ __launch_bounds__(256) void dense2_bn_kernel(
    const float* __restrict__ h, const float* __restrict__ sums,
    const float* __restrict__ sumsq, const float* __restrict__ gamma,
    const float* __restrict__ beta, const float* __restrict__ W2l,
    const float* __restrict__ W2r, const float* __restrict__ b2,
    unsigned char* __restrict__ t40, float* __restrict__ out)
{
    __shared__ float wlT[64 * 65];
    __shared__ float wrT[64 * 65];
    for (int idx = threadIdx.x; idx < 2560; idx += 256) {
        int f = idx >> 6, k = idx & 63;      // f < 40
        wlT[k * 65 + f] = W2l[idx];
        wrT[k * 65 + f] = W2r[idx];
    }
    __syncthreads();

    int f  = threadIdx.x & 63;
    int wv = threadIdx.x >> 6;
    int fc = (f < 40) ? f : 39;
    float wl[64], wr[64];
#pragma unroll
    for (int k = 0; k < 64; ++k) {
        wl[k] = wlT[k * 65 + fc];
        wr[k] = wrT[k * 65 + fc];
    }
    float bias = b2[fc];

    // BN finalize (redundant per block, ~10 insts)
    float inv_n = 1.0f / (float)N_NODES;
    float mu  = sums[f] * inv_n;
    float var = sumsq[f] * inv_n - mu * mu;
    float rs  = rsqrtf(var + BN_EPS);
    float sc  = gamma[f] * rs;
    float sh  = beta[f] - mu * sc;

    int node0 = blockIdx.x * 64;

    for (int nn = 0; nn < 16; ++nn) {
        int node = node0 + nn * 4 + wv;          // wave-uniform
        if (node < N_NODES) {
            float hvv = h[(size_t)node * 64 + f];
            float hn  = fmaxf(hvv * sc + sh, 0.f);   // BN + ReLU fused
            float ta = 0.f, ra = bias;
#pragma unroll
            for (int k = 0; k < 64; ++k) {
                float hb = bcast(hn, k);
                ta += hb * wl[k];
                ra += hb * wr[k];
            }
            if (f < 40) {
                t40[(size_t)node * 64 + f] = f2fp8(ta);
                out[(size_t)node * 40 + f] = ra;
            }
        }
    }
}

// ===========================================================================
// gather2 v9 (R18): v7 lane mapping + decode; same cross-node pipeline as
// gather1 v11 (ids 2-deep, next node's rounds 0/1 rows 1-deep).
// ===========================================================================
__global__ __launch_bounds__(256) void gather2_kernel(
    const unsigned int* __restrict__ t40, const int* __restrict__ offs,
    const int* __restrict__ nbr, float* __restrict__ out)
{
    __shared__ int soffs[65];
    int node0 = blockIdx.x * 64;
    if (threadIdx.x < 65) {
        int n = node0 + threadIdx.x;
        soffs[threadIdx.x] = offs[(n < N_NODES) ? n : N_NODES];
    }
    __syncthreads();

    int lane = threadIdx.x & 63;
    int q    = lane >> 4;          // quarter 0..3
    int m    = lane & 15;          // dword in row; cl<10 used
    int cl   = (m < 10) ? m : 9;
    int wv   = threadIdx.x >> 6;

    int idA, idB;
    {
        int bA = soffs[wv],     eA = soffs[wv + 1];
        int bB = soffs[wv + 4], eB = soffs[wv + 5];
        idA = nbr[max(min(bA + lane, eA - 1), 0)];
        idB = nbr[max(min(bB + lane, eB - 1), 0)];
    }
    unsigned int r0A[4], r1A[4], r0B[4], r1B[4];
    {
        int cnt0 = min(soffs[wv + 1] - soffs[wv], 64);
#pragma unroll
        for (int i = 0; i < 4; ++i) {
            int e   = 4 * i + q;
            int ide = __shfl(idA, max(min(e, cnt0 - 1), 0));
            r0A[i] = t40[(size_t)ide * 16 + cl];
        }
        if (cnt0 > 16) {
#pragma unroll
            for (int i = 0; i < 4; ++i) {
                int e   = 16 + 4 * i + q;
                int ide = __shfl(idA, min(e, cnt0 - 1));
                r1A[i] = t40[(size_t)ide * 16 + cl];
            }
        }
    }

    for (int nn = 0; nn < 16; ++nn) {
        int li   = nn * 4 + wv;
        int node = node0 + li;
        int beg = soffs[li], end = soffs[li + 1];
        int deg = end - beg;
        int cnt = min(deg, 64);

        int idC = 0;
        if (nn < 14) {
            int b = soffs[li + 8], e = soffs[li + 9];
            idC = nbr[max(min(b + lane, e - 1), 0)];
        }
        if (nn < 15) {
            int cntn = min(soffs[li + 5] - soffs[li + 4], 64);
#pragma unroll
            for (int i = 0; i < 4; ++i) {
                int e   = 4 * i + q;
                int ide = __shfl(idB, max(min(e, cntn - 1), 0));
                r0B[i] = t40[(size_t)ide * 16 + cl];
            }
            if (cntn > 16) {
#pragma unroll
                for (int i = 0; i < 4; ++i) {
                    int e   = 16 + 4 * i + q;
                    int ide = __shfl(idB, min(e, cntn - 1));
                    r1B[i] = t40[(size_t)ide * 16 + cl];
                }
            }
        }

        if (node < N_NODES) {                    // wave-uniform
            float4 o = make_float4(0.f, 0.f, 0.f, 0.f);
            if (lane < 10)
                o = ((const float4*)out)[(size_t)node * 10 + m];

            float a0=0,a1=0,a2=0,a3=0, b0=0,b1=0,b2=0,b3=0;
            // round 0 from prefetched regs
#pragma unroll
            for (int i = 0; i < 4; ++i) {
                int e = 4 * i + q;
                unsigned int w = (e < cnt) ? r0A[i] : 0u;
                v2f dlo = fp8x2<false>(w);
                v2f dhi = fp8x2<true>(w);
                if (i & 1) { b0 += dlo.x; b1 += dlo.y; b2 += dhi.x; b3 += dhi.y; }
                else       { a0 += dlo.x; a1 += dlo.y; a2 += dhi.x; a3 += dhi.y; }
            }
            if (cnt > 16) {                      // wave-uniform
#pragma unroll
                for (int i = 0; i < 4; ++i) {
                    int e = 16 + 4 * i + q;
                    unsigned int w = (e < cnt) ? r1A[i] : 0u;
                    v2f dlo = fp8x2<false>(w);
                    v2f dhi = fp8x2<true>(w);
                    if (i & 1) { b0 += dlo.x; b1 += dlo.y; b2 += dhi.x; b3 += dhi.y; }
                    else       { a0 += dlo.x; a1 += dlo.y; a2 += dhi.x; a3 += dhi.y; }
                }
                for (int r = 32; r < cnt; r += 16) {
#pragma unroll
                    for (int i = 0; i < 4; ++i) {
                        int e   = r + 4 * i + q;
                        int ide = __shfl(idA, min(e, cnt - 1));
                        unsigned int w = t40[(size_t)ide * 16 + cl];
                        w = (e < cnt) ? w : 0u;
                        v2f dlo = fp8x2<false>(w);
                        v2f dhi = fp8x2<true>(w);
                        if (i & 1) { b0 += dlo.x; b1 += dlo.y; b2 += dhi.x; b3 += dhi.y; }
                        else       { a0 += dlo.x; a1 += dlo.y; a2 += dhi.x; a3 += dhi.y; }
                    }
                }
            }
            for (int c = 64; c < deg; c += 64) {
                int idx = beg + c + lane;
                int idc = nbr[(idx < end) ? idx : (end - 1)];
                int cnt2 = min(deg - c, 64);
                for (int r = 0; r < cnt2; r += 16) {
#pragma unroll
                    for (int i = 0; i < 4; ++i) {
                        int e   = r + 4 * i + q;
                        int ide = __shfl(idc, min(e, cnt2 - 1));
                        unsigned int w = t40[(size_t)ide * 16 + cl];
                        w = (e < cnt2) ? w : 0u;
                        v2f dlo = fp8x2<false>(w);
                        v2f dhi = fp8x2<true>(w);
                        if (i & 1) { b0 += dlo.x; b1 += dlo.y; b2 += dhi.x; b3 += dhi.y; }
                        else       { a0 += dlo.x; a1 += dlo.y; a2 += dhi.x; a3 += dhi.y; }
                    }
                }
            }
            a0 += b0; a1 += b1; a2 += b2; a3 += b3;
            a0 += __shfl_xor(a0, 16); a0 += __shfl_xor(a0, 32);
            a1 += __shfl_xor(a1, 16); a1 += __shfl_xor(a1, 32);
            a2 += __shfl_xor(a2, 16); a2 += __shfl_xor(a2, 32);
            a3 += __shfl_xor(a3, 16); a3 += __shfl_xor(a3, 32);
            if (lane < 10) {
                float inv = 1.0f / (float)max(deg, 1);
                o.x += a0 * inv;
                o.y += a1 * inv;
                o.z += a2 * inv;
                o.w += a3 * inv;
                ((float4*)out)[(size_t)node * 10 + m] = o;
            }
        }

        idA = idB; idB = idC;
#pragma unroll
        for (int i = 0; i < 4; ++i) { r0A[i] = r0B[i]; r1A[i] = r1B[i]; }
    }
}

extern "C" void kernel_launch(void* const* d_in, const int* in_sizes, int n_in,
                              void* d_out, int out_size, void* d_ws, size_t ws_size,
                              hipStream_t stream)
{
    const float* x     = (const float*)d_in[0];
    const int*   ei    = (const int*)d_in[1];
    const float* W1l   = (const float*)d_in[2];
    const float* W1r   = (const float*)d_in[3];
    const float* b1    = (const float*)d_in[4];
    const float* gamma = (const float*)d_in[5];
    const float* beta  = (const float*)d_in[6];
    const float* W2l   = (const float*)d_in[7];
    const float* W2r   = (const float*)d_in[8];
    const float* b2    = (const float*)d_in[9];
    float* out = (float*)d_out;

    const int4* src4 = (const int4*)ei;              // edge_index[0], 16B-aligned
    const int4* dst4 = (const int4*)(ei + N_EDGES);  // edge_index[1]

    // workspace layout (~39 MB; 58.8 MB available). 64B-aligned arrays.
    float* ws    = (float*)d_ws;
    float* hv    = ws;                               // f32 [N*64]
    float* sums  = hv + (size_t)N_NODES * 64;        // 64
    float* sumsq = sums + 64;                        // 64
    float* padf  = sumsq + 64;                       // 128 pad
    int* deg    = (int*)(padf + 128);                // N
    int* offs   = deg + N_NODES;                     // N+16 (padded)
    int* cursor = offs + N_NODES + 16;               // N
    int* bsum   = cursor + N_NODES;                  // 128
    // scratch: u8 (fp8 N*64B) until gather1; t40 (fp8 N*64B) reuses it.
    unsigned char* u8 = (unsigned char*)(bsum + 128);
    unsigned char* t40 = u8;
    int* nbr    = (int*)(u8 + (size_t)N_NODES * 64); // E

    dim3 blk(256);

    // ---- CSR build (XCD-partitioned, int4 reads) + stat zeroing ----
    (void)hipMemsetAsync(sums, 0, (size_t)(256 + N_NODES) * sizeof(int), stream);
    histogram_xcd_kernel<<<FILL_CHUNKS * 8, blk, 0, stream>>>(dst4, deg);
    scan1_kernel<<<NB_SCAN, 1024, 0, stream>>>(deg, offs, bsum);
    scan3b_kernel<<<NB_SCAN, 1024, 0, stream>>>(offs, bsum, cursor);
    fill_xcd_kernel<<<FILL_CHUNKS * 8, blk, 0, stream>>>(src4, dst4, cursor, nbr);

    int dblocks = (N_NODES + 63) / 64;
    int gblocks = (N_NODES + 63) / 64;

    // ---- layer 1 ----
    dense1_lin_kernel<<<dblocks, blk, 0, stream>>>(x, W1l, W1r, b1, u8, hv);
    gather1_bn_kernel<<<gblocks, blk, 0, stream>>>(
        (const unsigned short*)u8, offs, nbr, hv, sums, sumsq);

    // ---- layer 2 (BN finalize + BN+ReLU fused into dense2) ----
    dense2_bn_kernel<<<dblocks, blk, 0, stream>>>(
        hv, sums, sumsq, gamma, beta, W2l, W2r, b2, t40, out);
    gather2_kernel<<<gblocks, blk, 0, stream>>>(
        (const unsigned int*)t40, offs, nbr, out);
}